// Round 11
// baseline (369.928 us; speedup 1.0000x reference)
//
#include <hip/hip_runtime.h>
#include <hip/hip_bf16.h>

// out[B,S,D_OUT] = x @ sign(W)^T + bias  ==  GEMM M=8192, N=4096, K=4096.
// Round 11: R10 (237us GEMM, MfmaUtil 50%) + one change: a03(t+1) reads move
// from ph1(t+1)-top (issue->wait, fully exposed) into ph4(t) (drain under
// CELL Q4 + barrier). Publication requirement: ph4's counted wait moves to
// ph4-TOP pre-barrier as vmcnt(0) — at that point B01[t+2] is not yet staged,
// so this drains exactly B23+A[t+1] (staged 2-3 phases back, ~1240cyc old);
// B01[t+2] still stays in flight across ph1..ph3 (R10's win preserved);
// ph3's vmcnt(6) ledger unchanged. Prologue pre-issues a03(0).

#define M_DIM 8192
#define N_DIM 4096
#define K_DIM 4096
#define BM 256
#define BN 256
#define BK 64
#define NT (K_DIM / BK)  // 64

typedef __attribute__((ext_vector_type(8))) short bf16x8;
typedef __attribute__((ext_vector_type(4))) float f32x4;
typedef __attribute__((ext_vector_type(8))) unsigned short u16x8;

// ---------- conversion helpers ----------

__device__ __forceinline__ unsigned short f2bf_rne(float f) {
    unsigned u = __float_as_uint(f);
    unsigned r = (u + 0x7FFFu + ((u >> 16) & 1u)) >> 16;
    return (unsigned short)r;
}

__device__ __forceinline__ unsigned short sign_bf(float f) {
    if (f == 0.0f) return 0;
    return (unsigned short)(0x3F80u | ((__float_as_uint(f) >> 16) & 0x8000u));
}

__global__ __launch_bounds__(256) void cvt_x_kernel(
    const float* __restrict__ in, unsigned short* __restrict__ out, long nvec8) {
    long i = (long)blockIdx.x * blockDim.x + threadIdx.x;
    if (i >= nvec8) return;
    const float4* p = reinterpret_cast<const float4*>(in) + i * 2;
    float4 v0 = p[0];
    float4 v1 = p[1];
    u16x8 r;
    r[0] = f2bf_rne(v0.x); r[1] = f2bf_rne(v0.y);
    r[2] = f2bf_rne(v0.z); r[3] = f2bf_rne(v0.w);
    r[4] = f2bf_rne(v1.x); r[5] = f2bf_rne(v1.y);
    r[6] = f2bf_rne(v1.z); r[7] = f2bf_rne(v1.w);
    reinterpret_cast<u16x8*>(out)[i] = r;
}

__global__ __launch_bounds__(256) void cvt_w_kernel(
    const float* __restrict__ in, unsigned short* __restrict__ out, long nvec8) {
    long i = (long)blockIdx.x * blockDim.x + threadIdx.x;
    if (i >= nvec8) return;
    const float4* p = reinterpret_cast<const float4*>(in) + i * 2;
    float4 v0 = p[0];
    float4 v1 = p[1];
    u16x8 r;
    r[0] = sign_bf(v0.x); r[1] = sign_bf(v0.y);
    r[2] = sign_bf(v0.z); r[3] = sign_bf(v0.w);
    r[4] = sign_bf(v1.x); r[5] = sign_bf(v1.y);
    r[6] = sign_bf(v1.z); r[7] = sign_bf(v1.w);
    reinterpret_cast<u16x8*>(out)[i] = r;
}

// ---------- async global->LDS ----------

__device__ __forceinline__ void GL16(const unsigned short* g, unsigned short* l) {
    __builtin_amdgcn_global_load_lds(
        (const __attribute__((address_space(1))) unsigned int*)g,
        (__attribute__((address_space(3))) unsigned int*)l, 16, 0, 0);
}

// ---------- inline-asm ds_read_b128 with immediate byte offset ----------

template<int OFS>
__device__ __forceinline__ bf16x8 DSR(const unsigned short* p) {
    bf16x8 r;
    auto lp = (const __attribute__((address_space(3))) unsigned short*)p;
    asm volatile("ds_read_b128 %0, %1 offset:%2"
                 : "=&v"(r) : "v"(lp), "i"(OFS));
    return r;
}

#define BARRIER asm volatile("s_barrier" ::: "memory")
#define VMCNT0  asm volatile("s_waitcnt vmcnt(0)" ::: "memory")
#define VMCNT6  asm volatile("s_waitcnt vmcnt(6)" ::: "memory")
#define LGKM0   asm volatile("s_waitcnt lgkmcnt(0)" ::: "memory")
#define SCHED0  __builtin_amdgcn_sched_barrier(0)
#define PRIO1   __builtin_amdgcn_s_setprio(1)
#define PRIO0   __builtin_amdgcn_s_setprio(0)

// 16-MFMA quadrant: 4 m-frags x 2 n-frags x 2 k-halves
#define CELL(MB, NB, Aa, Bb) \
    _Pragma("unroll") for (int m_ = 0; m_ < 4; ++m_) \
    _Pragma("unroll") for (int n_ = 0; n_ < 2; ++n_) \
    _Pragma("unroll") for (int kk_ = 0; kk_ < 2; ++kk_) \
        acc[(MB) + m_][(NB) + n_] = __builtin_amdgcn_mfma_f32_16x16x32_bf16( \
            Aa[m_][kk_], Bb[n_][kk_], acc[(MB) + m_][(NB) + n_], 0, 0, 0)

// ---------- 256x256 4-phase GEMM, counted vmcnt + a03-ahead ----------
// 512 thr = 8 waves (2M x 4N); wave out 128x64 = acc[8][4] f32x4.
// Per K-tile t (CUR=t&1):
//  ph1: bar | stage B23(t+1)->NXT | lgkm0 (a03',b01' pre-issued, covered)
//       | Q1=a03*b01 | rd b23(t)
//  ph2: bar | stage A(t+1)->NXT   | lgkm0 (b23) | Q2=a03*b23 | rd a47(t)
//  ph3: vmcnt(6) [confirms B01(t+1)] | bar | lgkm0 (a47) | Q3=a47*b01
//       | rd b01(t+1)<-NXT
//  ph4: vmcnt(0) [confirms B23+A(t+1); B01(t+2) not yet staged] | bar
//       | stage B01(t+2)->CUR | rd a03(t+1)<-NXT | Q4=a47*b23
// vmcnt ledger (in-order): ph3(t): B01[t+1](2)+B23[t+1](2)+A[t+1](4)=8 ->
// vmcnt6 drains B01[t+1]. ph4(t)-top: B23+A[t+1]=6 -> vmcnt0 drains all;
// B01[t+2] staged after -> in flight until ph3(t+1)'s vmcnt6. All waits
// precede the barrier that publishes; all reads follow it.

__global__ __launch_bounds__(512, 2) void gemm256h(
    const unsigned short* __restrict__ A,   // [M][K] bf16 bits
    const unsigned short* __restrict__ Bt,  // [N][K] bf16 bits (sign weights)
    const float* __restrict__ bias,         // [N]
    float* __restrict__ C)                  // [M][N] fp32
{
    __shared__ __align__(16) unsigned short As[2][BM * BK];  // 64 KiB
    __shared__ __align__(16) unsigned short Bs[2][BN * BK];  // 64 KiB

    const int tid  = threadIdx.x;
    const int lane = tid & 63;
    const int w    = tid >> 6;
    const int wr   = w >> 2;
    const int wc   = w & 3;

    // T1: XCD-aware bijective swizzle (grid = 512, divisible by 8)
    int bid = blockIdx.x;
    const int cpx = gridDim.x >> 3;
    bid = (bid & 7) * cpx + (bid >> 3);
    const int ntile = N_DIM / BN;  // 16
    const long brow = (long)(bid / ntile) * BM;
    const long bcol = (long)(bid % ntile) * BN;

    // staging lane geometry (inverse-swizzled global src, linear LDS dest)
    const int wrow8 = lane >> 3;
    const int colsw = ((lane & 7) ^ wrow8) * 8;
    const int arw_u = (w >> 2) * 128 + (w & 3) * 8;
    const int brw_u = (w >> 2) * 64 + (w & 3) * 8;
    const long aRow = brow + arw_u + wrow8;
    const long bRow = bcol + brw_u + wrow8;

#define GA(BUF, I, KT) GL16(A  + (aRow + (I) * 32) * (long)K_DIM + (colsw + (KT)), \
                            &As[BUF][(arw_u + (I) * 32) * 64])
#define GB(BUF, OFS, KT) GL16(Bt + (bRow + (OFS)) * (long)K_DIM + (colsw + (KT)), \
                              &Bs[BUF][(brw_u + (OFS)) * 64])

    // fragment read bases (swizzled), loop-invariant
    const int fr = lane & 15;
    const int fq = lane >> 4;
    const int rqu = (fq * 8) ^ ((lane & 7) << 3);
    const int aoff = (wr * 128 + fr) * 64 + rqu;
    const int boff = (wc * 64 + fr) * 64 + rqu;

    const unsigned short* As0k0 = &As[0][aoff];
    const unsigned short* As0k1 = &As[0][aoff ^ 32];
    const unsigned short* As1k0 = &As[1][aoff];
    const unsigned short* As1k1 = &As[1][aoff ^ 32];
    const unsigned short* Bs0k0 = &Bs[0][boff];
    const unsigned short* Bs0k1 = &Bs[0][boff ^ 32];
    const unsigned short* Bs1k0 = &Bs[1][boff];
    const unsigned short* Bs1k1 = &Bs[1][boff ^ 32];

    f32x4 acc[8][4];
#pragma unroll
    for (int m = 0; m < 8; ++m)
#pragma unroll
        for (int n = 0; n < 4; ++n) acc[m][n] = (f32x4){0.f, 0.f, 0.f, 0.f};

    bf16x8 a03[4][2], a47[4][2], b01[2][2], b23[2][2];

    // ----- prologue: tile0 (8 GL16 -> buf0) + tile1's B01 (2 -> buf1) -----
    GA(0, 0, 0); GA(0, 1, 0); GA(0, 2, 0); GA(0, 3, 0);
    GB(0, 0, 0); GB(0, 128, 0); GB(0, 32, 0); GB(0, 160, 0);
    GB(1, 0, BK); GB(1, 128, BK);
    VMCNT0;
    BARRIER;
    // pre-issue b01(t0) + a03(t0); certified at ph1(0)'s lgkm0 (one-time cost)
    b01[0][0] = DSR<0>(Bs0k0);    b01[0][1] = DSR<0>(Bs0k1);
    b01[1][0] = DSR<2048>(Bs0k0); b01[1][1] = DSR<2048>(Bs0k1);
    a03[0][0] = DSR<0>(As0k0);    a03[0][1] = DSR<0>(As0k1);
    a03[1][0] = DSR<2048>(As0k0); a03[1][1] = DSR<2048>(As0k1);
    a03[2][0] = DSR<4096>(As0k0); a03[2][1] = DSR<4096>(As0k1);
    a03[3][0] = DSR<6144>(As0k0); a03[3][1] = DSR<6144>(As0k1);

#define TILE_BODY(TT, CUR, NXT, pAc0, pAc1, pBc0, pBc1, pAn0, pAn1, pBn0, pBn1) { \
    const long kt1 = (long)((TT) + 1) * BK; \
    const long kt2 = (long)((TT) + 2) * BK; \
    const bool s1 = ((TT) + 1 < NT); \
    const bool s2 = ((TT) + 2 < NT); \
    /* ---- ph1: lgkm0 cheap (a03',b01' drained under prev Q4+barrier) ---- */ \
    BARRIER; \
    if (s1) { GB(NXT, 32, kt1); GB(NXT, 160, kt1); } \
    LGKM0; SCHED0; \
    PRIO1; CELL(0, 0, a03, b01); PRIO0; SCHED0; \
    b23[0][0] = DSR<4096>(pBc0); b23[0][1] = DSR<4096>(pBc1); \
    b23[1][0] = DSR<6144>(pBc0); b23[1][1] = DSR<6144>(pBc1); \
    /* ---- ph2 ---- */ \
    BARRIER; \
    if (s1) { GA(NXT, 0, kt1); GA(NXT, 1, kt1); GA(NXT, 2, kt1); GA(NXT, 3, kt1); } \
    LGKM0; SCHED0; \
    PRIO1; CELL(0, 2, a03, b23); PRIO0; SCHED0; \
    a47[0][0] = DSR<8192>(pAc0);  a47[0][1] = DSR<8192>(pAc1); \
    a47[1][0] = DSR<10240>(pAc0); a47[1][1] = DSR<10240>(pAc1); \
    a47[2][0] = DSR<12288>(pAc0); a47[2][1] = DSR<12288>(pAc1); \
    a47[3][0] = DSR<14336>(pAc0); a47[3][1] = DSR<14336>(pAc1); \
    /* ---- ph3: counted drain (B01[t+1] confirmed; B23/A[t+1] in flight) ---- */ \
    VMCNT6; \
    BARRIER; \
    LGKM0; SCHED0; \
    PRIO1; CELL(4, 0, a47, b01); PRIO0; SCHED0; \
    if (s1) { \
        b01[0][0] = DSR<0>(pBn0);    b01[0][1] = DSR<0>(pBn1); \
        b01[1][0] = DSR<2048>(pBn0); b01[1][1] = DSR<2048>(pBn1); \
    } \
    /* ---- ph4: confirm B23+A[t+1] pre-barrier; read a03(t+1) under Q4 ---- */ \
    VMCNT0; \
    BARRIER; \
    if (s2) { GB(CUR, 0, kt2); GB(CUR, 128, kt2); } \
    if (s1) { \
        a03[0][0] = DSR<0>(pAn0);    a03[0][1] = DSR<0>(pAn1); \
        a03[1][0] = DSR<2048>(pAn0); a03[1][1] = DSR<2048>(pAn1); \
        a03[2][0] = DSR<4096>(pAn0); a03[2][1] = DSR<4096>(pAn1); \
        a03[3][0] = DSR<6144>(pAn0); a03[3][1] = DSR<6144>(pAn1); \
    } \
    PRIO1; CELL(4, 2, a47, b23); PRIO0; SCHED0; \
}

    for (int t = 0; t < NT; t += 2) {
        TILE_BODY(t,     0, 1, As0k0, As0k1, Bs0k0, Bs0k1, As1k0, As1k1, Bs1k0, Bs1k1);
        TILE_BODY(t + 1, 1, 0, As1k0, As1k1, Bs1k0, Bs1k1, As0k0, As0k1, Bs0k0, Bs0k1);
    }
#undef TILE_BODY

    // ----- epilogue: C/D layout col = lane&15, row = (lane>>4)*4 + j -----
#pragma unroll
    for (int n = 0; n < 4; ++n) {
        const long cg = bcol + wc * 64 + n * 16 + fr;
        const float bv = bias[cg];
#pragma unroll
        for (int m = 0; m < 8; ++m) {
            const long rbase = brow + wr * 128 + m * 16 + fq * 4;
#pragma unroll
            for (int j = 0; j < 4; ++j)
                C[(rbase + j) * (long)N_DIM + cg] = acc[m][n][j] + bv;
        }
    }
}

// ---------- naive fallback ----------

__global__ __launch_bounds__(256) void naive_kernel(
    const float* __restrict__ x, const float* __restrict__ w,
    const float* __restrict__ bias, float* __restrict__ out, long total) {
    long gid = (long)blockIdx.x * blockDim.x + threadIdx.x;
    if (gid >= total) return;
    long m = gid / N_DIM, n = gid % N_DIM;
    const float* xr = x + m * (long)K_DIM;
    const float* wr = w + n * (long)K_DIM;
    float s = 0.f;
    for (int k = 0; k < K_DIM; ++k) {
        float wv = wr[k];
        float sg = (wv > 0.f) ? 1.f : ((wv < 0.f) ? -1.f : 0.f);
        s += xr[k] * sg;
    }
    out[gid] = s + bias[n];
}

// ---------- launch ----------

extern "C" void kernel_launch(void* const* d_in, const int* in_sizes, int n_in,
                              void* d_out, int out_size, void* d_ws, size_t ws_size,
                              hipStream_t stream) {
    const float* x    = (const float*)d_in[0];
    const float* w    = (const float*)d_in[1];
    const float* bias = (const float*)d_in[2];
    float* out = (float*)d_out;

    const size_t nA = (size_t)M_DIM * K_DIM;
    const size_t nB = (size_t)N_DIM * K_DIM;
    const size_t need_bytes = (nA + nB) * sizeof(unsigned short);

    if (ws_size >= need_bytes) {
        unsigned short* xb = (unsigned short*)d_ws;
        unsigned short* wb = xb + nA;
        {
            long nvec8 = (long)(nA / 8);
            cvt_x_kernel<<<(int)((nvec8 + 255) / 256), 256, 0, stream>>>(x, xb, nvec8);
        }
        {
            long nvec8 = (long)(nB / 8);
            cvt_w_kernel<<<(int)((nvec8 + 255) / 256), 256, 0, stream>>>(w, wb, nvec8);
        }
        dim3 grid((M_DIM / BM) * (N_DIM / BN));  // 512
        gemm256h<<<grid, 512, 0, stream>>>(xb, wb, bias, out);
    } else {
        long total = (long)M_DIM * N_DIM;
        naive_kernel<<<(int)((total + 255) / 256), 256, 0, stream>>>(x, w, bias, out, total);
    }
}

// Round 12
// 268.867 us; speedup vs baseline: 1.3759x; 1.3759x over previous
//
#include <hip/hip_runtime.h>
#include <hip/hip_bf16.h>

// out[B,S,D_OUT] = x @ sign(W)^T + bias  ==  GEMM M=8192, N=4096, K=4096.
// Round 12: consolidation. GEMM loop reverted byte-identical to R10 (best:
// 237us dispatch, MfmaUtil 50%, 1160 TF). R11's lesson: stage->drain needs
// >=3 phases + a CELL of cover (effective stage landing ~1.3-1.9k cyc under
// full-chip DMA load); R10's vmcnt placement is exactly at that horizon.
// Only change: cvt_x + cvt_w merged into one launch (block-uniform branch).

#define M_DIM 8192
#define N_DIM 4096
#define K_DIM 4096
#define BM 256
#define BN 256
#define BK 64
#define NT (K_DIM / BK)  // 64

typedef __attribute__((ext_vector_type(8))) short bf16x8;
typedef __attribute__((ext_vector_type(4))) float f32x4;
typedef __attribute__((ext_vector_type(8))) unsigned short u16x8;

// ---------- conversion helpers ----------

__device__ __forceinline__ unsigned short f2bf_rne(float f) {
    unsigned u = __float_as_uint(f);
    unsigned r = (u + 0x7FFFu + ((u >> 16) & 1u)) >> 16;
    return (unsigned short)r;
}

__device__ __forceinline__ unsigned short sign_bf(float f) {
    if (f == 0.0f) return 0;
    return (unsigned short)(0x3F80u | ((__float_as_uint(f) >> 16) & 0x8000u));
}

// Merged conversion: vec-index < nvec8_x -> bf16 cast of x; else sign(w).
// Boundary nvec8_x = 4 Mi is a multiple of blockDim -> block-uniform branch.
__global__ __launch_bounds__(256) void cvt_both_kernel(
    const float* __restrict__ x, const float* __restrict__ wgt,
    unsigned short* __restrict__ xb, unsigned short* __restrict__ wb,
    long nvec8_x, long nvec8_total) {
    long i = (long)blockIdx.x * blockDim.x + threadIdx.x;
    if (i >= nvec8_total) return;
    if (i < nvec8_x) {
        const float4* p = reinterpret_cast<const float4*>(x) + i * 2;
        float4 v0 = p[0];
        float4 v1 = p[1];
        u16x8 r;
        r[0] = f2bf_rne(v0.x); r[1] = f2bf_rne(v0.y);
        r[2] = f2bf_rne(v0.z); r[3] = f2bf_rne(v0.w);
        r[4] = f2bf_rne(v1.x); r[5] = f2bf_rne(v1.y);
        r[6] = f2bf_rne(v1.z); r[7] = f2bf_rne(v1.w);
        reinterpret_cast<u16x8*>(xb)[i] = r;
    } else {
        long j = i - nvec8_x;
        const float4* p = reinterpret_cast<const float4*>(wgt) + j * 2;
        float4 v0 = p[0];
        float4 v1 = p[1];
        u16x8 r;
        r[0] = sign_bf(v0.x); r[1] = sign_bf(v0.y);
        r[2] = sign_bf(v0.z); r[3] = sign_bf(v0.w);
        r[4] = sign_bf(v1.x); r[5] = sign_bf(v1.y);
        r[6] = sign_bf(v1.z); r[7] = sign_bf(v1.w);
        reinterpret_cast<u16x8*>(wb)[j] = r;
    }
}

// ---------- async global->LDS ----------

__device__ __forceinline__ void GL16(const unsigned short* g, unsigned short* l) {
    __builtin_amdgcn_global_load_lds(
        (const __attribute__((address_space(1))) unsigned int*)g,
        (__attribute__((address_space(3))) unsigned int*)l, 16, 0, 0);
}

// ---------- inline-asm ds_read_b128 with immediate byte offset ----------

template<int OFS>
__device__ __forceinline__ bf16x8 DSR(const unsigned short* p) {
    bf16x8 r;
    auto lp = (const __attribute__((address_space(3))) unsigned short*)p;
    asm volatile("ds_read_b128 %0, %1 offset:%2"
                 : "=&v"(r) : "v"(lp), "i"(OFS));
    return r;
}

#define BARRIER asm volatile("s_barrier" ::: "memory")
#define VMCNT0  asm volatile("s_waitcnt vmcnt(0)" ::: "memory")
#define VMCNT2  asm volatile("s_waitcnt vmcnt(2)" ::: "memory")
#define VMCNT6  asm volatile("s_waitcnt vmcnt(6)" ::: "memory")
#define LGKM0   asm volatile("s_waitcnt lgkmcnt(0)" ::: "memory")
#define SCHED0  __builtin_amdgcn_sched_barrier(0)
#define PRIO1   __builtin_amdgcn_s_setprio(1)
#define PRIO0   __builtin_amdgcn_s_setprio(0)

// 16-MFMA quadrant: 4 m-frags x 2 n-frags x 2 k-halves
#define CELL(MB, NB, Aa, Bb) \
    _Pragma("unroll") for (int m_ = 0; m_ < 4; ++m_) \
    _Pragma("unroll") for (int n_ = 0; n_ < 2; ++n_) \
    _Pragma("unroll") for (int kk_ = 0; kk_ < 2; ++kk_) \
        acc[(MB) + m_][(NB) + n_] = __builtin_amdgcn_mfma_f32_16x16x32_bf16( \
            Aa[m_][kk_], Bb[n_][kk_], acc[(MB) + m_][(NB) + n_], 0, 0, 0)

// ---------- 256x256 4-phase GEMM (R10 schedule, byte-identical) ----------
// 512 thr = 8 waves (2M x 4N); wave out 128x64 = acc[8][4] f32x4.
// Per K-tile t (CUR=t&1):
//  ph1: bar | stage B23(t+1)->NXT | rd a03(t) | lgkm0 | Q1=a03*b01 | rd b23(t)
//  ph2: bar | stage A(t+1)->NXT               | lgkm0 | Q2=a03*b23 | rd a47(t)
//  ph3: vmcnt(6) [confirms B01(t+1), staged ph4(t-1)] | bar | lgkm0
//       | Q3=a47*b01 | rd b01(t+1)<-NXT
//  ph4: bar | stage B01(t+2)->CUR | Q4=a47*b23
//       | vmcnt(s2?2:0) [confirms B23+A(t+1); leaves B01(t+2) in flight]
// vmcnt ledger (in-order retire): at ph3(t): outstanding = B01[t+1](2)+
// B23[t+1](2)+A[t+1](4) = 8 -> vmcnt(6) drains oldest 2 = B01[t+1].
// At ph4(t) end: outstanding = B23[t+1](2)+A[t+1](4)+B01[t+2](2) = 8 ->
// vmcnt(2) drains oldest 6 = B23+A[t+1], needed by ph1(t+1)'s reads.
// R11 lesson: do NOT move the ph4 wait pre-CELL (stage landing horizon
// ~1.3-1.9k cyc; Q4's cover is required). Tail t=NT-2: vmcnt(0).

__global__ __launch_bounds__(512, 2) void gemm256g(
    const unsigned short* __restrict__ A,   // [M][K] bf16 bits
    const unsigned short* __restrict__ Bt,  // [N][K] bf16 bits (sign weights)
    const float* __restrict__ bias,         // [N]
    float* __restrict__ C)                  // [M][N] fp32
{
    __shared__ __align__(16) unsigned short As[2][BM * BK];  // 64 KiB
    __shared__ __align__(16) unsigned short Bs[2][BN * BK];  // 64 KiB

    const int tid  = threadIdx.x;
    const int lane = tid & 63;
    const int w    = tid >> 6;
    const int wr   = w >> 2;
    const int wc   = w & 3;

    // T1: XCD-aware bijective swizzle (grid = 512, divisible by 8)
    int bid = blockIdx.x;
    const int cpx = gridDim.x >> 3;
    bid = (bid & 7) * cpx + (bid >> 3);
    const int ntile = N_DIM / BN;  // 16
    const long brow = (long)(bid / ntile) * BM;
    const long bcol = (long)(bid % ntile) * BN;

    // staging lane geometry (inverse-swizzled global src, linear LDS dest)
    const int wrow8 = lane >> 3;
    const int colsw = ((lane & 7) ^ wrow8) * 8;
    const int arw_u = (w >> 2) * 128 + (w & 3) * 8;
    const int brw_u = (w >> 2) * 64 + (w & 3) * 8;
    const long aRow = brow + arw_u + wrow8;
    const long bRow = bcol + brw_u + wrow8;

#define GA(BUF, I, KT) GL16(A  + (aRow + (I) * 32) * (long)K_DIM + (colsw + (KT)), \
                            &As[BUF][(arw_u + (I) * 32) * 64])
#define GB(BUF, OFS, KT) GL16(Bt + (bRow + (OFS)) * (long)K_DIM + (colsw + (KT)), \
                              &Bs[BUF][(brw_u + (OFS)) * 64])

    // fragment read bases (swizzled), loop-invariant
    const int fr = lane & 15;
    const int fq = lane >> 4;
    const int rqu = (fq * 8) ^ ((lane & 7) << 3);
    const int aoff = (wr * 128 + fr) * 64 + rqu;
    const int boff = (wc * 64 + fr) * 64 + rqu;

    const unsigned short* As0k0 = &As[0][aoff];
    const unsigned short* As0k1 = &As[0][aoff ^ 32];
    const unsigned short* As1k0 = &As[1][aoff];
    const unsigned short* As1k1 = &As[1][aoff ^ 32];
    const unsigned short* Bs0k0 = &Bs[0][boff];
    const unsigned short* Bs0k1 = &Bs[0][boff ^ 32];
    const unsigned short* Bs1k0 = &Bs[1][boff];
    const unsigned short* Bs1k1 = &Bs[1][boff ^ 32];

    f32x4 acc[8][4];
#pragma unroll
    for (int m = 0; m < 8; ++m)
#pragma unroll
        for (int n = 0; n < 4; ++n) acc[m][n] = (f32x4){0.f, 0.f, 0.f, 0.f};

    bf16x8 a03[4][2], a47[4][2], b01[2][2], b23[2][2];

    // ----- prologue: tile0 (8 GL16 -> buf0) + tile1's B01 (2 -> buf1) -----
    GA(0, 0, 0); GA(0, 1, 0); GA(0, 2, 0); GA(0, 3, 0);
    GB(0, 0, 0); GB(0, 128, 0); GB(0, 32, 0); GB(0, 160, 0);
    GB(1, 0, BK); GB(1, 128, BK);
    VMCNT0;
    BARRIER;
    // pre-issue b01(t=0); certified at ph1(0)'s lgkm0
    b01[0][0] = DSR<0>(Bs0k0);    b01[0][1] = DSR<0>(Bs0k1);
    b01[1][0] = DSR<2048>(Bs0k0); b01[1][1] = DSR<2048>(Bs0k1);

#define TILE_BODY(TT, CUR, NXT, pAc0, pAc1, pBc0, pBc1, pBn0, pBn1) { \
    const long kt1 = (long)((TT) + 1) * BK; \
    const long kt2 = (long)((TT) + 2) * BK; \
    const bool s1 = ((TT) + 1 < NT); \
    const bool s2 = ((TT) + 2 < NT); \
    /* ---- ph1 ---- */ \
    BARRIER; \
    if (s1) { GB(NXT, 32, kt1); GB(NXT, 160, kt1); } \
    a03[0][0] = DSR<0>(pAc0);    a03[0][1] = DSR<0>(pAc1); \
    a03[1][0] = DSR<2048>(pAc0); a03[1][1] = DSR<2048>(pAc1); \
    a03[2][0] = DSR<4096>(pAc0); a03[2][1] = DSR<4096>(pAc1); \
    a03[3][0] = DSR<6144>(pAc0); a03[3][1] = DSR<6144>(pAc1); \
    LGKM0; SCHED0; \
    PRIO1; CELL(0, 0, a03, b01); PRIO0; SCHED0; \
    b23[0][0] = DSR<4096>(pBc0); b23[0][1] = DSR<4096>(pBc1); \
    b23[1][0] = DSR<6144>(pBc0); b23[1][1] = DSR<6144>(pBc1); \
    /* ---- ph2 ---- */ \
    BARRIER; \
    if (s1) { GA(NXT, 0, kt1); GA(NXT, 1, kt1); GA(NXT, 2, kt1); GA(NXT, 3, kt1); } \
    LGKM0; SCHED0; \
    PRIO1; CELL(0, 2, a03, b23); PRIO0; SCHED0; \
    a47[0][0] = DSR<8192>(pAc0);  a47[0][1] = DSR<8192>(pAc1); \
    a47[1][0] = DSR<10240>(pAc0); a47[1][1] = DSR<10240>(pAc1); \
    a47[2][0] = DSR<12288>(pAc0); a47[2][1] = DSR<12288>(pAc1); \
    a47[3][0] = DSR<14336>(pAc0); a47[3][1] = DSR<14336>(pAc1); \
    /* ---- ph3: counted drain (B01[t+1] confirmed; B23/A[t+1] in flight) ---- */ \
    VMCNT6; \
    BARRIER; \
    LGKM0; SCHED0; \
    PRIO1; CELL(4, 0, a47, b01); PRIO0; SCHED0; \
    if (s1) { \
        b01[0][0] = DSR<0>(pBn0);    b01[0][1] = DSR<0>(pBn1); \
        b01[1][0] = DSR<2048>(pBn0); b01[1][1] = DSR<2048>(pBn1); \
    } \
    /* ---- ph4 ---- */ \
    BARRIER; \
    if (s2) { GB(CUR, 0, kt2); GB(CUR, 128, kt2); } \
    PRIO1; CELL(4, 2, a47, b23); PRIO0; SCHED0; \
    /* confirm B23+A[t+1] for ph1(t+1); leave B01[t+2] in flight */ \
    if (s2) { VMCNT2; } else { VMCNT0; } \
}

    for (int t = 0; t < NT; t += 2) {
        TILE_BODY(t,     0, 1, As0k0, As0k1, Bs0k0, Bs0k1, Bs1k0, Bs1k1);
        TILE_BODY(t + 1, 1, 0, As1k0, As1k1, Bs1k0, Bs1k1, Bs0k0, Bs0k1);
    }
#undef TILE_BODY

    // ----- epilogue: C/D layout col = lane&15, row = (lane>>4)*4 + j -----
#pragma unroll
    for (int n = 0; n < 4; ++n) {
        const long cg = bcol + wc * 64 + n * 16 + fr;
        const float bv = bias[cg];
#pragma unroll
        for (int m = 0; m < 8; ++m) {
            const long rbase = brow + wr * 128 + m * 16 + fq * 4;
#pragma unroll
            for (int j = 0; j < 4; ++j)
                C[(rbase + j) * (long)N_DIM + cg] = acc[m][n][j] + bv;
        }
    }
}

// ---------- naive fallback ----------

__global__ __launch_bounds__(256) void naive_kernel(
    const float* __restrict__ x, const float* __restrict__ w,
    const float* __restrict__ bias, float* __restrict__ out, long total) {
    long gid = (long)blockIdx.x * blockDim.x + threadIdx.x;
    if (gid >= total) return;
    long m = gid / N_DIM, n = gid % N_DIM;
    const float* xr = x + m * (long)K_DIM;
    const float* wr = w + n * (long)K_DIM;
    float s = 0.f;
    for (int k = 0; k < K_DIM; ++k) {
        float wv = wr[k];
        float sg = (wv > 0.f) ? 1.f : ((wv < 0.f) ? -1.f : 0.f);
        s += xr[k] * sg;
    }
    out[gid] = s + bias[n];
}

// ---------- launch ----------

extern "C" void kernel_launch(void* const* d_in, const int* in_sizes, int n_in,
                              void* d_out, int out_size, void* d_ws, size_t ws_size,
                              hipStream_t stream) {
    const float* x    = (const float*)d_in[0];
    const float* w    = (const float*)d_in[1];
    const float* bias = (const float*)d_in[2];
    float* out = (float*)d_out;

    const size_t nA = (size_t)M_DIM * K_DIM;
    const size_t nB = (size_t)N_DIM * K_DIM;
    const size_t need_bytes = (nA + nB) * sizeof(unsigned short);

    if (ws_size >= need_bytes) {
        unsigned short* xb = (unsigned short*)d_ws;
        unsigned short* wb = xb + nA;
        {
            long nvec8_x = (long)(nA / 8);
            long nvec8_total = (long)((nA + nB) / 8);
            int blocks = (int)((nvec8_total + 255) / 256);
            cvt_both_kernel<<<blocks, 256, 0, stream>>>(x, w, xb, wb,
                                                        nvec8_x, nvec8_total);
        }
        dim3 grid((M_DIM / BM) * (N_DIM / BN));  // 512
        gemm256g<<<grid, 512, 0, stream>>>(xb, wb, bias, out);
    } else {
        long total = (long)M_DIM * N_DIM;
        naive_kernel<<<(int)((total + 255) / 256), 256, 0, stream>>>(x, w, bias, out, total);
    }
}

// Round 13
// 265.798 us; speedup vs baseline: 1.3918x; 1.0115x over previous
//
#include <hip/hip_runtime.h>
#include <hip/hip_bf16.h>

// out[B,S,D_OUT] = x @ sign(W)^T + bias  ==  GEMM M=8192, N=4096, K=4096.
// Round 13: R12 + fine-grained read||MFMA interleave (counted lgkm sub-batches).
// Diagnosis: MFMA pipe 2484 cyc/tile and LDS pipe ~2000 cyc/tile currently
// serialize (phase = all-reads -> LGKM0 -> all-MFMA, barrier waits for the
// last wave through the shared LDS FIFO). Fix: ph1 splits a03's LGKM0 into
// LGKM(4)+LGKM(0) with 8 MFMA between; ph2 moves a47's 8 reads inside the
// CELL. Stages, vmcnt ledger, barriers, registers: byte-identical to R12.

#define M_DIM 8192
#define N_DIM 4096
#define K_DIM 4096
#define BM 256
#define BN 256
#define BK 64
#define NT (K_DIM / BK)  // 64

typedef __attribute__((ext_vector_type(8))) short bf16x8;
typedef __attribute__((ext_vector_type(4))) float f32x4;
typedef __attribute__((ext_vector_type(8))) unsigned short u16x8;

// ---------- conversion helpers ----------

__device__ __forceinline__ unsigned short f2bf_rne(float f) {
    unsigned u = __float_as_uint(f);
    unsigned r = (u + 0x7FFFu + ((u >> 16) & 1u)) >> 16;
    return (unsigned short)r;
}

__device__ __forceinline__ unsigned short sign_bf(float f) {
    if (f == 0.0f) return 0;
    return (unsigned short)(0x3F80u | ((__float_as_uint(f) >> 16) & 0x8000u));
}

// Merged conversion: vec-index < nvec8_x -> bf16 cast of x; else sign(w).
__global__ __launch_bounds__(256) void cvt_both_kernel(
    const float* __restrict__ x, const float* __restrict__ wgt,
    unsigned short* __restrict__ xb, unsigned short* __restrict__ wb,
    long nvec8_x, long nvec8_total) {
    long i = (long)blockIdx.x * blockDim.x + threadIdx.x;
    if (i >= nvec8_total) return;
    if (i < nvec8_x) {
        const float4* p = reinterpret_cast<const float4*>(x) + i * 2;
        float4 v0 = p[0];
        float4 v1 = p[1];
        u16x8 r;
        r[0] = f2bf_rne(v0.x); r[1] = f2bf_rne(v0.y);
        r[2] = f2bf_rne(v0.z); r[3] = f2bf_rne(v0.w);
        r[4] = f2bf_rne(v1.x); r[5] = f2bf_rne(v1.y);
        r[6] = f2bf_rne(v1.z); r[7] = f2bf_rne(v1.w);
        reinterpret_cast<u16x8*>(xb)[i] = r;
    } else {
        long j = i - nvec8_x;
        const float4* p = reinterpret_cast<const float4*>(wgt) + j * 2;
        float4 v0 = p[0];
        float4 v1 = p[1];
        u16x8 r;
        r[0] = sign_bf(v0.x); r[1] = sign_bf(v0.y);
        r[2] = sign_bf(v0.z); r[3] = sign_bf(v0.w);
        r[4] = sign_bf(v1.x); r[5] = sign_bf(v1.y);
        r[6] = sign_bf(v1.z); r[7] = sign_bf(v1.w);
        reinterpret_cast<u16x8*>(wb)[j] = r;
    }
}

// ---------- async global->LDS ----------

__device__ __forceinline__ void GL16(const unsigned short* g, unsigned short* l) {
    __builtin_amdgcn_global_load_lds(
        (const __attribute__((address_space(1))) unsigned int*)g,
        (__attribute__((address_space(3))) unsigned int*)l, 16, 0, 0);
}

// ---------- inline-asm ds_read_b128 with immediate byte offset ----------

template<int OFS>
__device__ __forceinline__ bf16x8 DSR(const unsigned short* p) {
    bf16x8 r;
    auto lp = (const __attribute__((address_space(3))) unsigned short*)p;
    asm volatile("ds_read_b128 %0, %1 offset:%2"
                 : "=&v"(r) : "v"(lp), "i"(OFS));
    return r;
}

#define BARRIER asm volatile("s_barrier" ::: "memory")
#define VMCNT0  asm volatile("s_waitcnt vmcnt(0)" ::: "memory")
#define VMCNT2  asm volatile("s_waitcnt vmcnt(2)" ::: "memory")
#define VMCNT6  asm volatile("s_waitcnt vmcnt(6)" ::: "memory")
#define LGKM0   asm volatile("s_waitcnt lgkmcnt(0)" ::: "memory")
#define LGKM4   asm volatile("s_waitcnt lgkmcnt(4)" ::: "memory")
#define SCHED0  __builtin_amdgcn_sched_barrier(0)
#define PRIO1   __builtin_amdgcn_s_setprio(1)
#define PRIO0   __builtin_amdgcn_s_setprio(0)

// 16-MFMA quadrant: 4 m-frags x 2 n-frags x 2 k-halves
#define CELL(MB, NB, Aa, Bb) \
    _Pragma("unroll") for (int m_ = 0; m_ < 4; ++m_) \
    _Pragma("unroll") for (int n_ = 0; n_ < 2; ++n_) \
    _Pragma("unroll") for (int kk_ = 0; kk_ < 2; ++kk_) \
        acc[(MB) + m_][(NB) + n_] = __builtin_amdgcn_mfma_f32_16x16x32_bf16( \
            Aa[m_][kk_], Bb[n_][kk_], acc[(MB) + m_][(NB) + n_], 0, 0, 0)

// 8-MFMA half-quadrant: 2 m-frags (AOFS..AOFS+1) x 2 n-frags x 2 k-halves
#define HCELL(MB, NB, Aa, AOFS, Bb) \
    _Pragma("unroll") for (int m_ = 0; m_ < 2; ++m_) \
    _Pragma("unroll") for (int n_ = 0; n_ < 2; ++n_) \
    _Pragma("unroll") for (int kk_ = 0; kk_ < 2; ++kk_) \
        acc[(MB) + m_][(NB) + n_] = __builtin_amdgcn_mfma_f32_16x16x32_bf16( \
            Aa[(AOFS) + m_][kk_], Bb[n_][kk_], acc[(MB) + m_][(NB) + n_], 0, 0, 0)

// ---------- 256x256 4-phase GEMM (R12 schedule + in-phase interleave) ----
// Per K-tile t (CUR=t&1):
//  ph1: bar | stage B23(t+1) | rd a03 x8 | LGKM(4) [certifies b01+a03[0..1]]
//       | 8 MFMA (m0-1) | LGKM(0) | 8 MFMA (m2-3) | rd b23 x4
//  ph2: bar | stage A(t+1) | lgkm0 [b23] | 8 MFMA | rd a47[0..1] x4
//       | 8 MFMA | rd a47[2..3] x4
//  ph3: vmcnt(6) | bar | lgkm0 [a47] | Q3 16 MFMA | rd b01(t+1) x4
//  ph4: bar | stage B01(t+2) | Q4 16 MFMA | vmcnt(s2?2:0)
// vmcnt ledger identical to R12 (proven). lgkm ledger ph1: entry <=4 (b01),
// +8 a03 -> LGKM(4) drains oldest 8 = b01(4)+a03[0..1](4).

__global__ __launch_bounds__(512, 2) void gemm256i(
    const unsigned short* __restrict__ A,   // [M][K] bf16 bits
    const unsigned short* __restrict__ Bt,  // [N][K] bf16 bits (sign weights)
    const float* __restrict__ bias,         // [N]
    float* __restrict__ C)                  // [M][N] fp32
{
    __shared__ __align__(16) unsigned short As[2][BM * BK];  // 64 KiB
    __shared__ __align__(16) unsigned short Bs[2][BN * BK];  // 64 KiB

    const int tid  = threadIdx.x;
    const int lane = tid & 63;
    const int w    = tid >> 6;
    const int wr   = w >> 2;
    const int wc   = w & 3;

    // T1: XCD-aware bijective swizzle (grid = 512, divisible by 8)
    int bid = blockIdx.x;
    const int cpx = gridDim.x >> 3;
    bid = (bid & 7) * cpx + (bid >> 3);
    const int ntile = N_DIM / BN;  // 16
    const long brow = (long)(bid / ntile) * BM;
    const long bcol = (long)(bid % ntile) * BN;

    // staging lane geometry (inverse-swizzled global src, linear LDS dest)
    const int wrow8 = lane >> 3;
    const int colsw = ((lane & 7) ^ wrow8) * 8;
    const int arw_u = (w >> 2) * 128 + (w & 3) * 8;
    const int brw_u = (w >> 2) * 64 + (w & 3) * 8;
    const long aRow = brow + arw_u + wrow8;
    const long bRow = bcol + brw_u + wrow8;

#define GA(BUF, I, KT) GL16(A  + (aRow + (I) * 32) * (long)K_DIM + (colsw + (KT)), \
                            &As[BUF][(arw_u + (I) * 32) * 64])
#define GB(BUF, OFS, KT) GL16(Bt + (bRow + (OFS)) * (long)K_DIM + (colsw + (KT)), \
                              &Bs[BUF][(brw_u + (OFS)) * 64])

    // fragment read bases (swizzled), loop-invariant
    const int fr = lane & 15;
    const int fq = lane >> 4;
    const int rqu = (fq * 8) ^ ((lane & 7) << 3);
    const int aoff = (wr * 128 + fr) * 64 + rqu;
    const int boff = (wc * 64 + fr) * 64 + rqu;

    const unsigned short* As0k0 = &As[0][aoff];
    const unsigned short* As0k1 = &As[0][aoff ^ 32];
    const unsigned short* As1k0 = &As[1][aoff];
    const unsigned short* As1k1 = &As[1][aoff ^ 32];
    const unsigned short* Bs0k0 = &Bs[0][boff];
    const unsigned short* Bs0k1 = &Bs[0][boff ^ 32];
    const unsigned short* Bs1k0 = &Bs[1][boff];
    const unsigned short* Bs1k1 = &Bs[1][boff ^ 32];

    f32x4 acc[8][4];
#pragma unroll
    for (int m = 0; m < 8; ++m)
#pragma unroll
        for (int n = 0; n < 4; ++n) acc[m][n] = (f32x4){0.f, 0.f, 0.f, 0.f};

    bf16x8 a03[4][2], a47[4][2], b01[2][2], b23[2][2];

    // ----- prologue: tile0 (8 GL16 -> buf0) + tile1's B01 (2 -> buf1) -----
    GA(0, 0, 0); GA(0, 1, 0); GA(0, 2, 0); GA(0, 3, 0);
    GB(0, 0, 0); GB(0, 128, 0); GB(0, 32, 0); GB(0, 160, 0);
    GB(1, 0, BK); GB(1, 128, BK);
    VMCNT0;
    BARRIER;
    // pre-issue b01(t=0); certified at ph1(0)'s LGKM(4)
    b01[0][0] = DSR<0>(Bs0k0);    b01[0][1] = DSR<0>(Bs0k1);
    b01[1][0] = DSR<2048>(Bs0k0); b01[1][1] = DSR<2048>(Bs0k1);

#define TILE_BODY(TT, CUR, NXT, pAc0, pAc1, pBc0, pBc1, pBn0, pBn1) { \
    const long kt1 = (long)((TT) + 1) * BK; \
    const long kt2 = (long)((TT) + 2) * BK; \
    const bool s1 = ((TT) + 1 < NT); \
    const bool s2 = ((TT) + 2 < NT); \
    /* ---- ph1: a03 reads split LGKM(4)/LGKM(0), MFMA between ---- */ \
    BARRIER; \
    if (s1) { GB(NXT, 32, kt1); GB(NXT, 160, kt1); } \
    a03[0][0] = DSR<0>(pAc0);    a03[0][1] = DSR<0>(pAc1); \
    a03[1][0] = DSR<2048>(pAc0); a03[1][1] = DSR<2048>(pAc1); \
    a03[2][0] = DSR<4096>(pAc0); a03[2][1] = DSR<4096>(pAc1); \
    a03[3][0] = DSR<6144>(pAc0); a03[3][1] = DSR<6144>(pAc1); \
    LGKM4; SCHED0; \
    PRIO1; HCELL(0, 0, a03, 0, b01); PRIO0; SCHED0; \
    LGKM0; SCHED0; \
    PRIO1; HCELL(2, 0, a03, 2, b01); PRIO0; SCHED0; \
    b23[0][0] = DSR<4096>(pBc0); b23[0][1] = DSR<4096>(pBc1); \
    b23[1][0] = DSR<6144>(pBc0); b23[1][1] = DSR<6144>(pBc1); \
    /* ---- ph2: a47 reads interleaved inside the CELL ---- */ \
    BARRIER; \
    if (s1) { GA(NXT, 0, kt1); GA(NXT, 1, kt1); GA(NXT, 2, kt1); GA(NXT, 3, kt1); } \
    LGKM0; SCHED0; \
    PRIO1; HCELL(0, 2, a03, 0, b23); PRIO0; SCHED0; \
    a47[0][0] = DSR<8192>(pAc0);  a47[0][1] = DSR<8192>(pAc1); \
    a47[1][0] = DSR<10240>(pAc0); a47[1][1] = DSR<10240>(pAc1); \
    SCHED0; \
    PRIO1; HCELL(2, 2, a03, 2, b23); PRIO0; SCHED0; \
    a47[2][0] = DSR<12288>(pAc0); a47[2][1] = DSR<12288>(pAc1); \
    a47[3][0] = DSR<14336>(pAc0); a47[3][1] = DSR<14336>(pAc1); \
    /* ---- ph3: counted drain (B01[t+1] confirmed; B23/A[t+1] in flight) ---- */ \
    VMCNT6; \
    BARRIER; \
    LGKM0; SCHED0; \
    PRIO1; CELL(4, 0, a47, b01); PRIO0; SCHED0; \
    if (s1) { \
        b01[0][0] = DSR<0>(pBn0);    b01[0][1] = DSR<0>(pBn1); \
        b01[1][0] = DSR<2048>(pBn0); b01[1][1] = DSR<2048>(pBn1); \
    } \
    /* ---- ph4 ---- */ \
    BARRIER; \
    if (s2) { GB(CUR, 0, kt2); GB(CUR, 128, kt2); } \
    PRIO1; CELL(4, 2, a47, b23); PRIO0; SCHED0; \
    /* confirm B23+A[t+1] for ph1(t+1); leave B01[t+2] in flight */ \
    if (s2) { VMCNT2; } else { VMCNT0; } \
}

    for (int t = 0; t < NT; t += 2) {
        TILE_BODY(t,     0, 1, As0k0, As0k1, Bs0k0, Bs0k1, Bs1k0, Bs1k1);
        TILE_BODY(t + 1, 1, 0, As1k0, As1k1, Bs1k0, Bs1k1, Bs0k0, Bs0k1);
    }
#undef TILE_BODY

    // ----- epilogue: C/D layout col = lane&15, row = (lane>>4)*4 + j -----
#pragma unroll
    for (int n = 0; n < 4; ++n) {
        const long cg = bcol + wc * 64 + n * 16 + fr;
        const float bv = bias[cg];
#pragma unroll
        for (int m = 0; m < 8; ++m) {
            const long rbase = brow + wr * 128 + m * 16 + fq * 4;
#pragma unroll
            for (int j = 0; j < 4; ++j)
                C[(rbase + j) * (long)N_DIM + cg] = acc[m][n][j] + bv;
        }
    }
}

// ---------- naive fallback ----------

__global__ __launch_bounds__(256) void naive_kernel(
    const float* __restrict__ x, const float* __restrict__ w,
    const float* __restrict__ bias, float* __restrict__ out, long total) {
    long gid = (long)blockIdx.x * blockDim.x + threadIdx.x;
    if (gid >= total) return;
    long m = gid / N_DIM, n = gid % N_DIM;
    const float* xr = x + m * (long)K_DIM;
    const float* wr = w + n * (long)K_DIM;
    float s = 0.f;
    for (int k = 0; k < K_DIM; ++k) {
        float wv = wr[k];
        float sg = (wv > 0.f) ? 1.f : ((wv < 0.f) ? -1.f : 0.f);
        s += xr[k] * sg;
    }
    out[gid] = s + bias[n];
}

// ---------- launch ----------

extern "C" void kernel_launch(void* const* d_in, const int* in_sizes, int n_in,
                              void* d_out, int out_size, void* d_ws, size_t ws_size,
                              hipStream_t stream) {
    const float* x    = (const float*)d_in[0];
    const float* w    = (const float*)d_in[1];
    const float* bias = (const float*)d_in[2];
    float* out = (float*)d_out;

    const size_t nA = (size_t)M_DIM * K_DIM;
    const size_t nB = (size_t)N_DIM * K_DIM;
    const size_t need_bytes = (nA + nB) * sizeof(unsigned short);

    if (ws_size >= need_bytes) {
        unsigned short* xb = (unsigned short*)d_ws;
        unsigned short* wb = xb + nA;
        {
            long nvec8_x = (long)(nA / 8);
            long nvec8_total = (long)((nA + nB) / 8);
            int blocks = (int)((nvec8_total + 255) / 256);
            cvt_both_kernel<<<blocks, 256, 0, stream>>>(x, w, xb, wb,
                                                        nvec8_x, nvec8_total);
        }
        dim3 grid((M_DIM / BM) * (N_DIM / BN));  // 512
        gemm256i<<<grid, 512, 0, stream>>>(xb, wb, bias, out);
    } else {
        long total = (long)M_DIM * N_DIM;
        naive_kernel<<<(int)((total + 255) / 256), 256, 0, stream>>>(x, w, bias, out, total);
    }
}